// Round 5
// baseline (541.520 us; speedup 1.0000x reference)
//
#include <hip/hip_runtime.h>
#include <hip/hip_bf16.h>
#include <math.h>

namespace {

constexpr int NA   = 21504;   // anchors (128^2 + 64^2 + 32^2)
constexpr int NA4  = NA / 4;  // float4 count along N
constexpr int NB   = 32;      // batch
constexpr int NC   = 80;      // classes
constexpr int BINS = 17;

constexpr int QFL_XB = 210;   // qfl blocks per batch
constexpr int QFL_IT = 8;     // float4 per thread  (210*256*8 = NA*NC/4)
constexpr int REG_XB = 21;    // reg blocks per batch (21*256*4 = NA)

// ws layout:
//   float[NB*QFL_XB*2]  qfl partials {loss_sum, pos_cnt}   @ float idx 0
//   float[NB*REG_XB*3]  reg partials {ce, gterm, mask}     @ float idx NB*QFL_XB*2
//   double[NB*3]        per-batch {qfl, dfl, giou}         @ byte 131072

constexpr int PQ_F = NB * QFL_XB * 2;   // 13440
constexpr size_t PB_OFF = 131072;

__device__ __forceinline__ float get4(const float4 &v, int a) {
  return a == 0 ? v.x : a == 1 ? v.y : a == 2 ? v.z : v.w;
}

template <int K>
__device__ __forceinline__ void block_reduce(float (&v)[K]) {
  #pragma unroll
  for (int off = 32; off > 0; off >>= 1) {
    #pragma unroll
    for (int i = 0; i < K; ++i) v[i] += __shfl_down(v[i], off);
  }
  __shared__ float s[K][4];
  const int wid = threadIdx.x >> 6, lane = threadIdx.x & 63;
  if (lane == 0) {
    #pragma unroll
    for (int i = 0; i < K; ++i) s[i][wid] = v[i];
  }
  __syncthreads();
  if (threadIdx.x == 0) {
    #pragma unroll
    for (int i = 0; i < K; ++i) v[i] = s[i][0] + s[i][1] + s[i][2] + s[i][3];
  }
}

__global__ __launch_bounds__(256) void qfl_kernel(const float *__restrict__ pred,
                                                  const float *__restrict__ tgt,
                                                  float *__restrict__ part) {
  const int b = blockIdx.y;
  const float4 *p4 = reinterpret_cast<const float4 *>(pred + (size_t)b * NA * NC);
  const float4 *t4 = reinterpret_cast<const float4 *>(tgt + (size_t)b * NA * NC);
  const int f0 = blockIdx.x * 256 + threadIdx.x;

  // Batch-issue ALL loads first: 16 dwordx4 in flight per wave (MLP), then compute.
  float4 pv[QFL_IT], tv[QFL_IT];
  #pragma unroll
  for (int it = 0; it < QFL_IT; ++it) pv[it] = p4[f0 + it * (QFL_XB * 256)];
  #pragma unroll
  for (int it = 0; it < QFL_IT; ++it) tv[it] = t4[f0 + it * (QFL_XB * 256)];

  float v[2] = {0.f, 0.f};
  #pragma unroll
  for (int it = 0; it < QFL_IT; ++it) {
    #pragma unroll
    for (int c = 0; c < 4; ++c) {
      const float p = get4(pv[it], c), t = get4(tv[it], c);
      const float e = __expf(-fabsf(p));            // exp(-|p|) <= 1
      const float bce = fmaxf(p, 0.f) - p * t + __logf(1.f + e);
      const float r = __builtin_amdgcn_rcpf(1.f + e);
      const float sig = (p >= 0.f) ? r : e * r;     // sigmoid(p)
      const float df = sig - t;
      v[0] += bce * df * df;
      v[1] += (t > 0.f) ? 1.f : 0.f;
    }
  }
  block_reduce<2>(v);
  if (threadIdx.x == 0) {
    const int o = (b * QFL_XB + blockIdx.x) * 2;
    part[o + 0] = v[0];
    part[o + 1] = v[1];
  }
}

__global__ __launch_bounds__(256) void reg_kernel(const float *__restrict__ reg,
                                                  const float *__restrict__ gt,
                                                  const float *__restrict__ anch,
                                                  const float *__restrict__ strides,
                                                  float *__restrict__ part) {
  const int b = blockIdx.y;
  const int n4 = blockIdx.x * 256 + threadIdx.x;   // float4 index along N

  // ---- targets + mask (4 anchors) ----
  const float4 *g4 = reinterpret_cast<const float4 *>(gt + (size_t)b * 4 * NA);
  float4 gv[4];
  #pragma unroll
  for (int k = 0; k < 4; ++k) gv[k] = g4[k * NA4 + n4];

  float mask[4], tk[4][4];  // [anchor][side]
  #pragma unroll
  for (int a = 0; a < 4; ++a) {
    bool fin = false;
    #pragma unroll
    for (int k = 0; k < 4; ++k) fin = fin || !isinf(get4(gv[k], a));
    mask[a] = fin ? 1.f : 0.f;
    #pragma unroll
    for (int k = 0; k < 4; ++k) tk[a][k] = fin ? get4(gv[k], a) : 0.f;
  }

  // ---- per-side log-softmax: DFL ce + expected distance ----
  const float4 *r4 = reinterpret_cast<const float4 *>(reg + (size_t)b * 4 * BINS * NA);
  float ce[4] = {0.f, 0.f, 0.f, 0.f};
  float d[4][4];  // [anchor][side]
  #pragma unroll
  for (int k = 0; k < 4; ++k) {
    float4 x[BINS];
    #pragma unroll
    for (int j = 0; j < BINS; ++j) x[j] = r4[(size_t)(k * BINS + j) * NA4 + n4];
    #pragma unroll
    for (int a = 0; a < 4; ++a) {
      float m = get4(x[0], a);
      #pragma unroll
      for (int j = 1; j < BINS; ++j) m = fmaxf(m, get4(x[j], a));
      float se = 0.f, sj = 0.f;
      #pragma unroll
      for (int j = 0; j < BINS; ++j) {
        const float e = __expf(get4(x[j], a) - m);
        se += e;
        sj += e * (float)j;
      }
      d[a][k] = sj / se;
      const float logZ = m + __logf(se);
      const float t = tk[a][k];
      const int tl = (int)t;
      const float wr = t - (float)tl, wl = 1.f - wr;
      float xl = 0.f, xr = 0.f;
      #pragma unroll
      for (int j = 0; j < BINS; ++j) {
        const float xv = get4(x[j], a);
        xl = (j == tl) ? xv : xl;
        xr = (j == tl + 1) ? xv : xr;
      }
      ce[a] += (logZ - xl) * wl + (logZ - xr) * wr;
    }
  }

  // ---- GIoU (4 anchors) ----
  const float4 sv = reinterpret_cast<const float4 *>(strides)[n4];
  const float4 av0 = reinterpret_cast<const float4 *>(anch)[n4 * 2 + 0]; // x0 y0 x1 y1
  const float4 av1 = reinterpret_cast<const float4 *>(anch)[n4 * 2 + 1]; // x2 y2 x3 y3
  float vsum[3] = {0.f, 0.f, 0.f};
  #pragma unroll
  for (int a = 0; a < 4; ++a) {
    const float s = get4(sv, a);
    const float ax = (a == 0) ? av0.x : (a == 1) ? av0.z : (a == 2) ? av1.x : av1.z;
    const float ay = (a == 0) ? av0.y : (a == 1) ? av0.w : (a == 2) ? av1.y : av1.w;
    const float W = 1024.f, H = 1024.f;
    const float px1 = fminf(fmaxf(ax - d[a][0] * s, 0.f), W);
    const float py1 = fminf(fmaxf(ay - d[a][1] * s, 0.f), H);
    const float px2 = fminf(fmaxf(ax + d[a][2] * s, 0.f), W);
    const float py2 = fminf(fmaxf(ay + d[a][3] * s, 0.f), H);
    const float tx1 = fminf(fmaxf(ax - tk[a][0] * s, 0.f), W);
    const float ty1 = fminf(fmaxf(ay - tk[a][1] * s, 0.f), H);
    const float tx2 = fminf(fmaxf(ax + tk[a][2] * s, 0.f), W);
    const float ty2 = fminf(fmaxf(ay + tk[a][3] * s, 0.f), H);
    const float iw = fmaxf(fminf(px2, tx2) - fmaxf(px1, tx1), 0.f);
    const float ih = fmaxf(fminf(py2, ty2) - fmaxf(py1, ty1), 0.f);
    const float inter = iw * ih;
    const float area_p = (px2 - px1) * (py2 - py1);
    const float area_t = (tx2 - tx1) * (ty2 - ty1);
    const float uni = area_p + area_t - inter;
    const float iou = inter / fmaxf(uni, 1e-9f);
    const float cw = fmaxf(px2, tx2) - fminf(px1, tx1);
    const float ch = fmaxf(py2, ty2) - fminf(py1, ty1);
    const float area_c = cw * ch;
    const float giou = iou - (area_c - uni) / fmaxf(area_c, 1e-9f);
    vsum[0] += ce[a] * mask[a];
    vsum[1] += (1.f - giou) * mask[a];
    vsum[2] += mask[a];
  }

  block_reduce<3>(vsum);
  if (threadIdx.x == 0) {
    const int o = (b * REG_XB + blockIdx.x) * 3;
    part[o + 0] = vsum[0];
    part[o + 1] = vsum[1];
    part[o + 2] = vsum[2];
  }
}

__global__ __launch_bounds__(256) void finalize1(const float *__restrict__ pq,
                                                 const float *__restrict__ pr,
                                                 double *__restrict__ pb) {
  const int b = blockIdx.x;
  float v[5] = {0.f, 0.f, 0.f, 0.f, 0.f};
  for (int i = threadIdx.x; i < QFL_XB; i += 256) {
    v[0] += pq[(b * QFL_XB + i) * 2 + 0];
    v[1] += pq[(b * QFL_XB + i) * 2 + 1];
  }
  for (int i = threadIdx.x; i < REG_XB; i += 256) {
    v[2] += pr[(b * REG_XB + i) * 3 + 0];   // ce
    v[3] += pr[(b * REG_XB + i) * 3 + 1];   // gterm
    v[4] += pr[(b * REG_XB + i) * 3 + 2];   // mask count
  }
  block_reduce<5>(v);
  if (threadIdx.x == 0) {
    const double lsum = v[0], lcnt = v[1], ce = v[2], gs = v[3], msk = v[4];
    pb[b * 3 + 0] = lsum / (lcnt + 0.001);
    pb[b * 3 + 1] = ce / (4.0 * msk + 0.001);
    pb[b * 3 + 2] = (msk == 0.0) ? 0.0 : gs / fmax(msk, 1.0);
  }
}

__global__ void finalize2(const double *__restrict__ pb, float *__restrict__ out) {
  if (threadIdx.x == 0) {
    double q = 0., d = 0., g = 0.;
    for (int b = 0; b < NB; ++b) {
      q += pb[b * 3 + 0];
      d += pb[b * 3 + 1];
      g += pb[b * 3 + 2];
    }
    out[0] = (float)(q / (double)NB);
    out[1] = (float)(d / (double)NB);
    out[2] = (float)(g / (double)NB);
  }
}

} // namespace

extern "C" void kernel_launch(void *const *d_in, const int *in_sizes, int n_in,
                              void *d_out, int out_size, void *d_ws, size_t ws_size,
                              hipStream_t stream) {
  const float *gt_qfl  = (const float *)d_in[0];  // (B, N, C)
  const float *gt_dfl  = (const float *)d_in[1];  // (B, 4, N)
  const float *anch    = (const float *)d_in[2];  // (N, 2)
  const float *strides = (const float *)d_in[3];  // (N,)
  const float *p_cls   = (const float *)d_in[4];  // (B, N, C)
  const float *p_reg   = (const float *)d_in[5];  // (B, 4, BINS, N)
  (void)in_sizes; (void)n_in; (void)out_size; (void)ws_size;

  float *pq = (float *)d_ws;
  float *pr = pq + PQ_F;
  double *pb = (double *)((char *)d_ws + PB_OFF);

  dim3 gq(QFL_XB, NB);
  qfl_kernel<<<gq, 256, 0, stream>>>(p_cls, gt_qfl, pq);

  dim3 gr(REG_XB, NB);
  reg_kernel<<<gr, 256, 0, stream>>>(p_reg, gt_dfl, anch, strides, pr);

  finalize1<<<NB, 256, 0, stream>>>(pq, pr, pb);
  finalize2<<<1, 64, 0, stream>>>(pb, (float *)d_out);
}